// Round 1
// baseline (37.856 us; speedup 1.0000x reference)
//
#include <hip/hip_runtime.h>

#define NG 48
#define NC 16
#define NPTS (NG * NG * NG)
#define CUTMAX 2.7001f   // 1.5 * max(vdw) = 2.7, tiny margin (val is 0 at cutoff, so safe)
#define E2F 7.3890561f
#define NINE_OVER_E2 1.2180175f

// brick of grid points per 64-thread (1-wave) block: 2 x 2 x 16
#define BRX 2
#define BRY 2
#define BRZ 16
#define CAP 256          // candidate-list capacity (expected ~60-90, Poisson tail ~0)

__device__ __constant__ float c_vdw[4] = {1.52f, 1.7f, 1.55f, 1.8f};

__global__ __launch_bounds__(64)
void density_kernel(const float* __restrict__ coords,
                    const int* __restrict__ ch_idx,
                    const int* __restrict__ fg,
                    float* __restrict__ out, int natoms)
{
    __shared__ float4 sA[CAP];   // x, y, z, cut2 = (1.5r)^2
    __shared__ float4 sB[CAP];   // -2/r^2, 4/(E2 r^2), 12/(E2 r), as_float(chan mask)

    const int tid = threadIdx.x;            // 0..63, one wave
    const int bz = blockIdx.x;              // 0..2
    const int by = blockIdx.y;              // 0..23
    const int bx = blockIdx.z;              // 0..23
    const int tz = tid & 15;
    const int ty = (tid >> 4) & 1;
    const int tx = tid >> 5;

    const int gx = bx * BRX + tx;
    const int gy = by * BRY + ty;
    const int gz = bz * BRZ + tz;
    const float px = gx * 0.5f, py = gy * 0.5f, pz = gz * 0.5f;

    // extended bounding box of this brick's points
    const float lox = bx * (BRX * 0.5f) - CUTMAX;
    const float hix = bx * (BRX * 0.5f) + (BRX - 1) * 0.5f + CUTMAX;
    const float loy = by * (BRY * 0.5f) - CUTMAX;
    const float hiy = by * (BRY * 0.5f) + (BRY - 1) * 0.5f + CUTMAX;
    const float loz = bz * (BRZ * 0.5f) - CUTMAX;
    const float hiz = bz * (BRZ * 0.5f) + (BRZ - 1) * 0.5f + CUTMAX;

    // ---- deterministic ballot-ordered compaction of in-box atoms into LDS ----
    int cnt = 0;
    #pragma unroll 4
    for (int base = 0; base < natoms; base += 64) {
        const int a = base + tid;
        const bool valid = a < natoms;
        float ax = 1e30f, ay = 1e30f, az = 1e30f;
        if (valid) {
            ax = coords[a * 3 + 0];
            ay = coords[a * 3 + 1];
            az = coords[a * 3 + 2];
        }
        const bool pred = (ax > lox) & (ax < hix) &
                          (ay > loy) & (ay < hiy) &
                          (az > loz) & (az < hiz);
        const unsigned long long m = __ballot(pred);
        if (pred) {
            const int ofs = cnt + __popcll(m & ((1ull << tid) - 1ull));
            if (ofs < CAP) {
                const int ci = ch_idx[a];
                const int f  = fg[a];
                const float r  = c_vdw[ci];
                const float r2 = r * r;
                // channel mask: one_hot(ci) + one_hot(c1) + one_hot(c2), all disjoint
                int c1 = (f == 14) ? 4 : ((f == 15) ? 6 : f + 4);
                if (f == 12 || f == 13) c1 = -1;
                const int c2 = (f == 14) ? 5 : ((f == 15) ? 9 : -1);
                int mask = 1 << ci;
                if (c1 >= 0) mask |= 1 << c1;
                if (c2 >= 0) mask |= 1 << c2;
                sA[ofs] = make_float4(ax, ay, az, 2.25f * r2);
                sB[ofs] = make_float4(-2.0f / r2,
                                      4.0f / (E2F * r2),
                                      12.0f / (E2F * r),
                                      __int_as_float(mask));
            }
        }
        cnt += __popcll(m);
    }
    if (cnt > CAP) cnt = CAP;
    __syncthreads();

    // ---- gather over the candidate list ----
    float acc[NC];
    #pragma unroll
    for (int c = 0; c < NC; ++c) acc[c] = 0.0f;

    #pragma unroll 2
    for (int i = 0; i < cnt; ++i) {
        const float4 rA = sA[i];                 // wave-uniform broadcast read
        const float dx = px - rA.x;
        const float dy = py - rA.y;
        const float dz = pz - rA.z;
        const float d2 = dx * dx + dy * dy + dz * dz;
        if (d2 < rA.w) {                         // d < 1.5r
            const float4 rB = sB[i];
            const float r2 = rA.w * (4.0f / 9.0f);   // (1.5r)^2 * 4/9 = r^2
            const float d  = sqrtf(d2);
            const float f1 = __expf(rB.x * d2);                       // exp(-2 d2/r2)
            const float f2 = fmaf(rB.y, d2, fmaf(-rB.z, d, NINE_OVER_E2));
            const float val = (d2 < r2) ? f1 : f2;
            const int chan = __builtin_amdgcn_readfirstlane(__float_as_int(rB.w));
            #pragma unroll
            for (int c = 0; c < NC; ++c)
                if (chan & (1 << c)) acc[c] += val;  // scalar-branched, exec-masked add
        }
    }

    const int pbase = (gx * NG + gy) * NG + gz;
    #pragma unroll
    for (int c = 0; c < NC; ++c)
        out[c * NPTS + pbase] = acc[c];
}

extern "C" void kernel_launch(void* const* d_in, const int* in_sizes, int n_in,
                              void* d_out, int out_size, void* d_ws, size_t ws_size,
                              hipStream_t stream) {
    (void)n_in; (void)d_ws; (void)ws_size; (void)out_size;
    const float* coords = (const float*)d_in[0];
    const int* ch = (const int*)d_in[1];
    const int* fgp = (const int*)d_in[2];
    float* out = (float*)d_out;
    const int natoms = in_sizes[0] / 3;

    dim3 grid(NG / BRZ, NG / BRY, NG / BRX);   // (3, 24, 24)
    density_kernel<<<grid, 64, 0, stream>>>(coords, ch, fgp, out, natoms);
}

// Round 2
// 24.834 us; speedup vs baseline: 1.5244x; 1.5244x over previous
//
#include <hip/hip_runtime.h>

#define NG 48
#define NC 16
#define NPTS (NG * NG * NG)
#define E2F 7.3890561f
#define NINE_OVER_E2 1.2180175f

#define BR 4            // 4x4x4 grid-point brick per block
#define CAP 128         // candidate capacity (expected ~41, +13 sigma headroom)

__device__ __constant__ float c_vdw[4] = {1.52f, 1.7f, 1.55f, 1.8f};

// ---- prep: pack per-atom data once ----
__global__ void prep_kernel(const float* __restrict__ coords,
                            const int* __restrict__ ch_idx,
                            const int* __restrict__ fg,
                            float4* __restrict__ atomA,
                            float4* __restrict__ atomB, int natoms)
{
    const int i = blockIdx.x * blockDim.x + threadIdx.x;
    if (i >= natoms) return;
    const float x = coords[3 * i + 0];
    const float y = coords[3 * i + 1];
    const float z = coords[3 * i + 2];
    const int ci = ch_idx[i];
    const int f  = fg[i];
    const float r  = c_vdw[ci];
    const float r2 = r * r;
    int c1 = (f == 14) ? 4 : ((f == 15) ? 6 : f + 4);
    if (f == 12 || f == 13) c1 = -1;
    const int c2 = (f == 14) ? 5 : ((f == 15) ? 9 : -1);
    int mask = 1 << ci;
    if (c1 >= 0) mask |= 1 << c1;
    if (c2 >= 0) mask |= 1 << c2;
    atomA[i] = make_float4(x, y, z, 1.5f * r);                      // w = cutoff
    atomB[i] = make_float4(-2.0f / r2, 4.0f / (E2F * r2),
                           12.0f / (E2F * r), __int_as_float(mask));
}

// ---- main: 256 threads = 4 waves; brick 4x4x4; candidates split across waves ----
__global__ __launch_bounds__(256)
void density_kernel(const float4* __restrict__ atomA,
                    const float4* __restrict__ atomB,
                    float* __restrict__ out, int natoms)
{
    __shared__ float4 sA[CAP];
    __shared__ float4 sB[CAP];
    __shared__ int sCnt[4];
    __shared__ float sRed[4][NC][64];

    const int t = threadIdx.x;
    const int w = t >> 6;          // wave id 0..3
    const int l = t & 63;          // lane
    const int bz = blockIdx.x, by = blockIdx.y, bx = blockIdx.z;

    const int tz = l & 3, ty = (l >> 2) & 3, tx = l >> 4;
    const int gx = bx * BR + tx, gy = by * BR + ty, gz = bz * BR + tz;
    const float px = gx * 0.5f, py = gy * 0.5f, pz = gz * 0.5f;

    // brick point extents (margin applied per-atom below)
    const float blox = bx * 2.0f, bhix = blox + 1.5f;
    const float bloy = by * 2.0f, bhiy = bloy + 1.5f;
    const float bloz = bz * 2.0f, bhiz = bloz + 1.5f;

    // ---- cooperative 256-thread compaction, deterministic order ----
    int cnt = 0;
    for (int base = 0; base < natoms; base += 256) {
        const int a = base + t;
        float4 pA;
        bool pred = false;
        if (a < natoms) {
            pA = atomA[a];
            const float cut = pA.w;
            pred = (pA.x > blox - cut) & (pA.x < bhix + cut) &
                   (pA.y > bloy - cut) & (pA.y < bhiy + cut) &
                   (pA.z > bloz - cut) & (pA.z < bhiz + cut);
        }
        const unsigned long long m = __ballot(pred);
        if (l == 0) sCnt[w] = __popcll(m);
        __syncthreads();
        int ofs = cnt;
        #pragma unroll
        for (int w2 = 0; w2 < 4; ++w2) {
            const int c = sCnt[w2];
            if (w2 < w) ofs += c;
            cnt += c;
        }
        if (pred) {
            const int o = ofs + __popcll(m & ((1ull << l) - 1ull));
            if (o < CAP) { sA[o] = pA; sB[o] = atomB[a]; }
        }
        __syncthreads();   // protect sCnt before next chunk
    }
    if (cnt > CAP) cnt = CAP;

    // ---- gather: wave w takes candidates w, w+4, ... ----
    float acc[NC];
    #pragma unroll
    for (int c = 0; c < NC; ++c) acc[c] = 0.0f;

    for (int i = w; i < cnt; i += 4) {
        const float4 A = sA[i];                  // wave-uniform broadcast
        const float dx = px - A.x;
        const float dy = py - A.y;
        const float dz = pz - A.z;
        const float d2 = fmaf(dx, dx, fmaf(dy, dy, dz * dz));
        const float cut2 = A.w * A.w;
        if (d2 < cut2) {
            const float4 B = sB[i];
            const float r2 = cut2 * (4.0f / 9.0f);
            const float d  = sqrtf(d2);
            const float f1 = __expf(B.x * d2);
            const float f2 = fmaf(B.y, d2, fmaf(-B.z, d, NINE_OVER_E2));
            const float val = (d2 < r2) ? f1 : f2;
            const int chan = __builtin_amdgcn_readfirstlane(__float_as_int(B.w));
            #pragma unroll
            for (int c = 0; c < NC; ++c)
                if (chan & (1 << c)) acc[c] += val;   // scalar-branched
        }
    }

    // ---- cross-wave reduction ----
    #pragma unroll
    for (int c = 0; c < NC; ++c) sRed[w][c][l] = acc[c];
    __syncthreads();

    const int pbase = (gx * NG + gy) * NG + gz;
    #pragma unroll
    for (int k = 0; k < 4; ++k) {
        const int c = w * 4 + k;
        const float s = sRed[0][c][l] + sRed[1][c][l] +
                        sRed[2][c][l] + sRed[3][c][l];
        out[c * NPTS + pbase] = s;
    }
}

extern "C" void kernel_launch(void* const* d_in, const int* in_sizes, int n_in,
                              void* d_out, int out_size, void* d_ws, size_t ws_size,
                              hipStream_t stream) {
    (void)n_in; (void)ws_size; (void)out_size;
    const float* coords = (const float*)d_in[0];
    const int* ch = (const int*)d_in[1];
    const int* fgp = (const int*)d_in[2];
    float* out = (float*)d_out;
    const int natoms = in_sizes[0] / 3;

    float4* atomA = (float4*)d_ws;
    float4* atomB = atomA + natoms;

    prep_kernel<<<(natoms + 255) / 256, 256, 0, stream>>>(coords, ch, fgp, atomA, atomB, natoms);
    dim3 grid(NG / BR, NG / BR, NG / BR);   // 12 x 12 x 12
    density_kernel<<<grid, 256, 0, stream>>>(atomA, atomB, out, natoms);
}

// Round 3
// 23.497 us; speedup vs baseline: 1.6111x; 1.0569x over previous
//
#include <hip/hip_runtime.h>

#define NG 48
#define NC 16
#define NPTS (NG * NG * NG)
#define E2F 7.3890561f
#define NINE_OVER_E2 1.2180175f

#define BR 4            // 4x4x4 grid-point brick per block
#define SEGCAP 48       // per-wave segment capacity (expected ~7, ~15 sigma headroom)

__device__ __constant__ float c_vdw[4] = {1.52f, 1.7f, 1.55f, 1.8f};

// ---- prep: pack per-atom data once ----
__global__ void prep_kernel(const float* __restrict__ coords,
                            const int* __restrict__ ch_idx,
                            const int* __restrict__ fg,
                            float4* __restrict__ atomA,
                            float4* __restrict__ atomB, int natoms)
{
    const int i = blockIdx.x * blockDim.x + threadIdx.x;
    if (i >= natoms) return;
    const float x = coords[3 * i + 0];
    const float y = coords[3 * i + 1];
    const float z = coords[3 * i + 2];
    const int ci = ch_idx[i];
    const int f  = fg[i];
    const float r  = c_vdw[ci];
    const float r2 = r * r;
    int c1 = (f == 14) ? 4 : ((f == 15) ? 6 : f + 4);
    if (f == 12 || f == 13) c1 = -1;
    const int c2 = (f == 14) ? 5 : ((f == 15) ? 9 : -1);
    int mask = 1 << ci;
    if (c1 >= 0) mask |= 1 << c1;
    if (c2 >= 0) mask |= 1 << c2;
    atomA[i] = make_float4(x, y, z, 1.5f * r);                      // w = cutoff
    atomB[i] = make_float4(-2.0f / r2, 4.0f / (E2F * r2),
                           12.0f / (E2F * r), __int_as_float(mask));
}

// ---- main: 4 waves; brick 4x4x4; wave-private compaction, one barrier ----
__global__ __launch_bounds__(256)
void density_kernel(const float4* __restrict__ atomA,
                    const float4* __restrict__ atomB,
                    float* __restrict__ out, int natoms)
{
    __shared__ float4 sA[4 * SEGCAP];
    __shared__ float4 sB[4 * SEGCAP];
    __shared__ int sCnt[4];
    __shared__ float sRed[4][NC][64];

    const int t = threadIdx.x;
    const int w = t >> 6;          // wave id 0..3
    const int l = t & 63;          // lane
    const int bz = blockIdx.x, by = blockIdx.y, bx = blockIdx.z;

    const int tz = l & 3, ty = (l >> 2) & 3, tx = l >> 4;
    const int gx = bx * BR + tx, gy = by * BR + ty, gz = bz * BR + tz;
    const float px = gx * 0.5f, py = gy * 0.5f, pz = gz * 0.5f;

    // brick point extents
    const float blox = bx * 2.0f, bhix = blox + 1.5f;
    const float bloy = by * 2.0f, bhiy = bloy + 1.5f;
    const float bloz = bz * 2.0f, bhiz = bloz + 1.5f;

    // ---- wave-private compaction: wave w scans its quarter of atoms ----
    const int quarter = (natoms + 3) >> 2;                 // 512 for N=2048
    const int a0 = w * quarter;
    const int a1 = min(a0 + quarter, natoms);
    int myCnt = 0;
    for (int base = a0; base < a1; base += 64) {
        const int a = base + l;
        float4 pA;
        bool pred = false;
        if (a < a1) {
            pA = atomA[a];
            const float cut = pA.w;
            // sphere-vs-AABB: squared distance from atom to brick box
            const float ddx = fmaxf(fmaxf(blox - pA.x, pA.x - bhix), 0.0f);
            const float ddy = fmaxf(fmaxf(bloy - pA.y, pA.y - bhiy), 0.0f);
            const float ddz = fmaxf(fmaxf(bloz - pA.z, pA.z - bhiz), 0.0f);
            pred = fmaf(ddx, ddx, fmaf(ddy, ddy, ddz * ddz)) < cut * cut;
        }
        const unsigned long long m = __ballot(pred);
        if (pred) {
            const int o = myCnt + __popcll(m & ((1ull << l) - 1ull));
            if (o < SEGCAP) {
                sA[w * SEGCAP + o] = pA;
                sB[w * SEGCAP + o] = atomB[a];
            }
        }
        myCnt += __popcll(m);
    }
    if (l == 0) sCnt[w] = (myCnt > SEGCAP) ? SEGCAP : myCnt;
    __syncthreads();

    const int c0 = sCnt[0], c1 = sCnt[1], c2 = sCnt[2], c3 = sCnt[3];

    // ---- gather: wave w takes every 4th candidate of each segment ----
    float acc[NC];
    #pragma unroll
    for (int c = 0; c < NC; ++c) acc[c] = 0.0f;

    #pragma unroll 1
    for (int s = 0; s < 4; ++s) {
        const int cs = (s == 0) ? c0 : (s == 1) ? c1 : (s == 2) ? c2 : c3;
        const int segbase = s * SEGCAP;
        #pragma unroll 2
        for (int i = w; i < cs; i += 4) {
            const float4 A = sA[segbase + i];     // broadcast b128
            const float4 B = sB[segbase + i];     // issued together (MLP)
            const float dx = px - A.x;
            const float dy = py - A.y;
            const float dz = pz - A.z;
            const float d2 = fmaf(dx, dx, fmaf(dy, dy, dz * dz));
            const float cut2 = A.w * A.w;
            if (d2 < cut2) {
                const float r2 = cut2 * (4.0f / 9.0f);
                const float d  = sqrtf(d2);
                const float f1 = __expf(B.x * d2);
                const float f2 = fmaf(B.y, d2, fmaf(-B.z, d, NINE_OVER_E2));
                const float val = (d2 < r2) ? f1 : f2;
                const int chan = __builtin_amdgcn_readfirstlane(__float_as_int(B.w));
                #pragma unroll
                for (int c = 0; c < NC; ++c)
                    if (chan & (1 << c)) acc[c] += val;   // scalar-branched
            }
        }
    }

    // ---- cross-wave reduction ----
    #pragma unroll
    for (int c = 0; c < NC; ++c) sRed[w][c][l] = acc[c];
    __syncthreads();

    const int pbase = (gx * NG + gy) * NG + gz;
    #pragma unroll
    for (int k = 0; k < 4; ++k) {
        const int c = w * 4 + k;
        const float s = sRed[0][c][l] + sRed[1][c][l] +
                        sRed[2][c][l] + sRed[3][c][l];
        out[c * NPTS + pbase] = s;
    }
}

extern "C" void kernel_launch(void* const* d_in, const int* in_sizes, int n_in,
                              void* d_out, int out_size, void* d_ws, size_t ws_size,
                              hipStream_t stream) {
    (void)n_in; (void)ws_size; (void)out_size;
    const float* coords = (const float*)d_in[0];
    const int* ch = (const int*)d_in[1];
    const int* fgp = (const int*)d_in[2];
    float* out = (float*)d_out;
    const int natoms = in_sizes[0] / 3;

    float4* atomA = (float4*)d_ws;
    float4* atomB = atomA + natoms;

    prep_kernel<<<(natoms + 255) / 256, 256, 0, stream>>>(coords, ch, fgp, atomA, atomB, natoms);
    dim3 grid(NG / BR, NG / BR, NG / BR);   // 12 x 12 x 12
    density_kernel<<<grid, 256, 0, stream>>>(atomA, atomB, out, natoms);
}